// Round 2
// baseline (293.823 us; speedup 1.0000x reference)
//
#include <hip/hip_runtime.h>

// PennSkipGramModel forward: mean over B of
//   -logsig(clip(u_l·v_l)) + -logsig(clip(u_r·v_r))
//   + sum_k -logsig(-clip(u_l·neg_l[k])) + sum_k -logsig(-clip(u_r·neg_r[k]))
//
// Layout: 16 lanes per batch element; lane j holds row float4s #j and #(j+16)
// (row = 128 fp32 = 32 float4).
//
// R1 lesson: full-prefetch source order got the scheduler to keep ~8-10
// float4 loads in flight (VGPR 60), but __launch_bounds__(256,3) throttled
// occupancy to 12 waves/CU and the MLP gain was cancelled. The scheduler
// chose 60 VGPRs *voluntarily* under a 170 cap, so a (256,6) cap (85 VGPR)
// keeps the same pipeline depth while allowing 8 waves/SIMD. This round is
// the discriminator: latency/wave-slot-bound -> big win; gather-bandwidth
// ceiling -> null, and we're at the roofline.

#define HV4   32        // float4s per 128-float row
#define BATCH 65536
#define K     5

__device__ __forceinline__ float dot4(float4 a, float4 b) {
    return a.x * b.x + a.y * b.y + a.z * b.z + a.w * b.w;
}

__device__ __forceinline__ float red16(float v) {
    v += __shfl_xor(v, 8, 16);
    v += __shfl_xor(v, 4, 16);
    v += __shfl_xor(v, 2, 16);
    v += __shfl_xor(v, 1, 16);
    return v;   // full sum in all 16 lanes
}

__device__ __forceinline__ float clip10(float x) {
    return fminf(fmaxf(x, -10.0f), 10.0f);
}

__global__ __launch_bounds__(256, 6) void skipgram_fwd(
    const float* __restrict__ u_l, const float* __restrict__ u_r,
    const float* __restrict__ v_l, const float* __restrict__ v_r,
    const int* __restrict__ pos_u, const int* __restrict__ pos_vl,
    const int* __restrict__ pos_vr, const int* __restrict__ neg_vl,
    const int* __restrict__ neg_vr, float* __restrict__ out)
{
    const int tid  = threadIdx.x;
    const int lane = tid & 15;      // lane within 16-lane group
    const int grp  = tid >> 4;      // 0..15 groups per block
    const int b    = (blockIdx.x << 4) + grp;

    // ---- phase 0: all index loads (13 independent scalars) ----
    const int iu  = pos_u[b];
    const int ivl = pos_vl[b];
    const int ivr = pos_vr[b];
    int inl[K], inr[K];
    #pragma unroll
    for (int k = 0; k < K; ++k) {
        inl[k] = neg_vl[b * K + k];
        inr[k] = neg_vr[b * K + k];
    }

    // ---- phase 1: issue ALL 28 row loads, issue order == use order ----
    const float4* ULr = (const float4*)u_l + (size_t)iu * HV4;
    const float4* URr = (const float4*)u_r + (size_t)iu * HV4;
    float4 ul0 = ULr[lane], ul1 = ULr[lane + 16];
    float4 ur0 = URr[lane], ur1 = URr[lane + 16];

    const float4* VLr = (const float4*)v_l + (size_t)ivl * HV4;
    const float4* VRr = (const float4*)v_r + (size_t)ivr * HV4;
    float4 vl0 = VLr[lane], vl1 = VLr[lane + 16];
    float4 vr0 = VRr[lane], vr1 = VRr[lane + 16];

    float4 nl0[K], nl1[K], nr0[K], nr1[K];
    #pragma unroll
    for (int k = 0; k < K; ++k) {
        const float4* NL = (const float4*)v_l + (size_t)inl[k] * HV4;
        const float4* NR = (const float4*)v_r + (size_t)inr[k] * HV4;
        nl0[k] = NL[lane]; nl1[k] = NL[lane + 16];
        nr0[k] = NR[lane]; nr1[k] = NR[lane + 16];
    }

    // Keep loads above the compute (scheduler may still stage them in
    // chunks of ~8-10 under the pressure cap — that's fine, that's the
    // pipeline depth we measured at VGPR=60).
    __builtin_amdgcn_sched_barrier(0);

    // ---- phase 2: compute; waitcnt drains partially in issue order ----
    float sl = red16(dot4(ul0, vl0) + dot4(ul1, vl1));
    float sr = red16(dot4(ur0, vr0) + dot4(ur1, vr1));

    // -log_sigmoid(x) = log(1 + exp(-x)),  x already clipped to [-10,10]
    float acc = __logf(1.0f + __expf(-clip10(sl)))
              + __logf(1.0f + __expf(-clip10(sr)));

    #pragma unroll
    for (int k = 0; k < K; ++k) {
        float snl = red16(dot4(ul0, nl0[k]) + dot4(ul1, nl1[k]));
        float snr = red16(dot4(ur0, nr0[k]) + dot4(ur1, nr1[k]));
        // -log_sigmoid(-x) = log(1 + exp(x))
        acc += __logf(1.0f + __expf(clip10(snl)))
             + __logf(1.0f + __expf(clip10(snr)));
    }

    // block reduction: one value per 16-lane group -> one atomic per block
    __shared__ float smem[16];
    if (lane == 0) smem[grp] = acc;
    __syncthreads();
    if (tid == 0) {
        float s = 0.0f;
        #pragma unroll
        for (int i = 0; i < 16; ++i) s += smem[i];
        atomicAdd(out, s * (1.0f / BATCH));
    }
}

extern "C" void kernel_launch(void* const* d_in, const int* in_sizes, int n_in,
                              void* d_out, int out_size, void* d_ws, size_t ws_size,
                              hipStream_t stream) {
    const float* u_l   = (const float*)d_in[0];
    const float* u_r   = (const float*)d_in[1];
    const float* v_l   = (const float*)d_in[2];
    const float* v_r   = (const float*)d_in[3];
    const int* pos_u   = (const int*)d_in[4];
    const int* pos_vl  = (const int*)d_in[5];
    const int* pos_vr  = (const int*)d_in[6];
    const int* neg_vl  = (const int*)d_in[7];
    const int* neg_vr  = (const int*)d_in[8];
    float* out = (float*)d_out;

    // d_out is poisoned (0xAA) before every timed launch — zero it on-stream.
    hipMemsetAsync(out, 0, sizeof(float), stream);

    skipgram_fwd<<<BATCH / 16, 256, 0, stream>>>(
        u_l, u_r, v_l, v_r, pos_u, pos_vl, pos_vr, neg_vl, neg_vr, out);
}

// Round 3
// 228.498 us; speedup vs baseline: 1.2859x; 1.2859x over previous
//
#include <hip/hip_runtime.h>

// PennSkipGramModel forward: mean over B of
//   -logsig(clip(u_l·v_l)) + -logsig(clip(u_r·v_r))
//   + sum_k -logsig(-clip(u_l·neg_l[k])) + sum_k -logsig(-clip(u_r·neg_r[k]))
//
// R2 lesson: 16-lane×float4 full prefetch needs 112 payload VGPRs; under a
// (256,6) cap the compiler spilled it to scratch (WRITE_SIZE 128B -> 209MB,
// dur 85 -> 155us). Fix the geometry, not the regalloc:
//
//   64 lanes (one wave) per batch element, float2 per lane per row.
//   - one global_load_dwordx2 = one whole 512B row, perfectly contiguous
//   - ALL 14 row loads prefetched = 28 payload VGPRs (fits 8 waves/SIMD)
//   - b is wave-uniform (readfirstlane) -> index loads become s_load,
//     row bases live in SGPRs -> minimal VGPR addressing overhead
//
// Max MLP (14 outstanding/wave) AND max occupancy (8 waves/SIMD), no spills.

#define BATCH 65536
#define K     5

__device__ __forceinline__ float red64(float v) {
    v += __shfl_xor(v, 32);
    v += __shfl_xor(v, 16);
    v += __shfl_xor(v, 8);
    v += __shfl_xor(v, 4);
    v += __shfl_xor(v, 2);
    v += __shfl_xor(v, 1);
    return v;   // full sum in all 64 lanes
}

__device__ __forceinline__ float clip10(float x) {
    return fminf(fmaxf(x, -10.0f), 10.0f);
}

__device__ __forceinline__ float dot2(float2 a, float2 b) {
    return a.x * b.x + a.y * b.y;
}

__global__ __launch_bounds__(1024) void skipgram_fwd(
    const float* __restrict__ u_l, const float* __restrict__ u_r,
    const float* __restrict__ v_l, const float* __restrict__ v_r,
    const int* __restrict__ pos_u, const int* __restrict__ pos_vl,
    const int* __restrict__ pos_vr, const int* __restrict__ neg_vl,
    const int* __restrict__ neg_vr, float* __restrict__ out)
{
    const int tid  = threadIdx.x;
    const int lane = tid & 63;
    // wave id within block; readfirstlane makes it provably wave-uniform so
    // index loads scalarize (s_load) and row bases land in SGPRs.
    const int wid  = __builtin_amdgcn_readfirstlane(tid >> 6);   // 0..15
    const int b    = (blockIdx.x << 4) + wid;

    // ---- phase 0: 13 wave-uniform index loads (scalar) ----
    const int iu  = pos_u[b];
    const int ivl = pos_vl[b];
    const int ivr = pos_vr[b];
    int inl[K], inr[K];
    #pragma unroll
    for (int k = 0; k < K; ++k) {
        inl[k] = neg_vl[b * K + k];
        inr[k] = neg_vr[b * K + k];
    }

    // ---- phase 1: all 14 row loads (float2/lane = 512B/row/instr) ----
    // 64 float2 per 128-float row
    const float2* ULr = (const float2*)u_l + ((size_t)iu  << 6);
    const float2* URr = (const float2*)u_r + ((size_t)iu  << 6);
    const float2* VLr = (const float2*)v_l + ((size_t)ivl << 6);
    const float2* VRr = (const float2*)v_r + ((size_t)ivr << 6);

    float2 ul = ULr[lane];
    float2 ur = URr[lane];
    float2 vl = VLr[lane];
    float2 vr = VRr[lane];

    float2 nl[K], nr[K];
    #pragma unroll
    for (int k = 0; k < K; ++k) {
        nl[k] = ((const float2*)v_l + ((size_t)inl[k] << 6))[lane];
        nr[k] = ((const float2*)v_r + ((size_t)inr[k] << 6))[lane];
    }

    // Payload is only 28 VGPRs — pinning loads above compute is spill-safe.
    __builtin_amdgcn_sched_barrier(0);

    // ---- phase 2: compute ----
    float sl = red64(dot2(ul, vl));
    float sr = red64(dot2(ur, vr));

    // -log_sigmoid(x) = log(1 + exp(-x)),  x clipped to [-10,10]
    float acc = __logf(1.0f + __expf(-clip10(sl)))
              + __logf(1.0f + __expf(-clip10(sr)));

    #pragma unroll
    for (int k = 0; k < K; ++k) {
        float snl = red64(dot2(ul, nl[k]));
        float snr = red64(dot2(ur, nr[k]));
        // -log_sigmoid(-x) = log(1 + exp(x))
        acc += __logf(1.0f + __expf(clip10(snl)))
             + __logf(1.0f + __expf(clip10(snr)));
    }

    // ---- block reduction: 16 waves -> 1 atomic per block (4096 total) ----
    __shared__ float smem[16];
    if (lane == 0) smem[wid] = acc;
    __syncthreads();
    if (tid == 0) {
        float s = 0.0f;
        #pragma unroll
        for (int i = 0; i < 16; ++i) s += smem[i];
        atomicAdd(out, s * (1.0f / BATCH));
    }
}

extern "C" void kernel_launch(void* const* d_in, const int* in_sizes, int n_in,
                              void* d_out, int out_size, void* d_ws, size_t ws_size,
                              hipStream_t stream) {
    const float* u_l   = (const float*)d_in[0];
    const float* u_r   = (const float*)d_in[1];
    const float* v_l   = (const float*)d_in[2];
    const float* v_r   = (const float*)d_in[3];
    const int* pos_u   = (const int*)d_in[4];
    const int* pos_vl  = (const int*)d_in[5];
    const int* pos_vr  = (const int*)d_in[6];
    const int* neg_vl  = (const int*)d_in[7];
    const int* neg_vr  = (const int*)d_in[8];
    float* out = (float*)d_out;

    // d_out is poisoned (0xAA) before every timed launch — zero it on-stream.
    hipMemsetAsync(out, 0, sizeof(float), stream);

    skipgram_fwd<<<BATCH / 16, 1024, 0, stream>>>(
        u_l, u_r, v_l, v_r, pos_u, pos_vl, pos_vr, neg_vl, neg_vr, out);
}